// Round 14
// baseline (365.470 us; speedup 1.0000x reference)
//
#include <hip/hip_runtime.h>
#include <math.h>

#define B_ 32
#define T_ 1024
#define C_ 768
#define M_ (B_ * T_)   // 32768

typedef __attribute__((ext_vector_type(8))) short bf16x8;
typedef __attribute__((ext_vector_type(4))) float f32x4;
typedef __attribute__((ext_vector_type(8))) unsigned short u16x8;
typedef __attribute__((address_space(1))) const void g_void;
typedef __attribute__((address_space(3))) void lds_void;

__device__ __forceinline__ unsigned short f2bf(float f) {
  union { float f; unsigned int u; } v; v.f = f;
  unsigned int u = v.u;
  u += 0x7fffu + ((u >> 16) & 1u);   // RNE
  return (unsigned short)(u >> 16);
}
__device__ __forceinline__ float b2f(unsigned short h) {
  union { unsigned int u; float f; } v; v.u = ((unsigned int)h) << 16;
  return v.f;
}
__device__ __forceinline__ float blo(unsigned int p) {   // low bf16 of packed pair
  union { unsigned int u; float f; } v; v.u = p << 16;
  return v.f;
}
__device__ __forceinline__ float bhi(unsigned int p) {   // high bf16 of packed pair
  union { unsigned int u; float f; } v; v.u = p & 0xffff0000u;
  return v.f;
}

// ---------------------------------------------------------------------------
// prep: fused {4x weight f32->bf16 convert} + {time-shift mix x->xk,xv,xr}
// ---------------------------------------------------------------------------
#define WPB 288                      // blocks per weight matrix
#define WBLK (4 * WPB)               // 1152
#define MBLK ((M_ * C_ / 8) / 256)   // 12288

__global__ __launch_bounds__(256) void prep(const float* __restrict__ x,
                                            const float* __restrict__ tmk,
                                            const float* __restrict__ tmv,
                                            const float* __restrict__ tmr,
                                            const float* __restrict__ Wk,
                                            const float* __restrict__ Wv,
                                            const float* __restrict__ Wr,
                                            const float* __restrict__ Wo,
                                            unsigned short* __restrict__ wbk,
                                            unsigned short* __restrict__ wbv,
                                            unsigned short* __restrict__ wbr,
                                            unsigned short* __restrict__ wbo,
                                            unsigned short* __restrict__ ok,
                                            unsigned short* __restrict__ ov,
                                            unsigned short* __restrict__ orr) {
  if (blockIdx.x < WBLK) {
    const int sel = blockIdx.x / WPB;              // 0..3
    const int wi = blockIdx.x % WPB;
    const float* src = (sel == 0) ? Wk : (sel == 1) ? Wv : (sel == 2) ? Wr : Wo;
    unsigned short* dst = (sel == 0) ? wbk : (sel == 1) ? wbv : (sel == 2) ? wbr : wbo;
    const int gi = wi * 256 + threadIdx.x;
    const float* p = src + (size_t)gi * 8;
    float v[8];
    *(float4*)&v[0] = *(const float4*)p;
    *(float4*)&v[4] = *(const float4*)(p + 4);
    u16x8 o;
#pragma unroll
    for (int i = 0; i < 8; ++i) o[i] = f2bf(v[i]);
    *(u16x8*)(dst + (size_t)gi * 8) = o;
    return;
  }

  const unsigned int gi = (blockIdx.x - WBLK) * 256u + threadIdx.x;
  const int m = gi / (C_ / 8);
  const int c8 = (gi % (C_ / 8)) * 8;
  const float* xp = x + (size_t)m * C_ + c8;
  float xv8[8], xx8[8], t8[8];
  *(float4*)&xv8[0] = *(const float4*)xp;
  *(float4*)&xv8[4] = *(const float4*)(xp + 4);
  if ((m & (T_ - 1)) != 0) {
    *(float4*)&xx8[0] = *(const float4*)(xp - C_);
    *(float4*)&xx8[4] = *(const float4*)(xp - C_ + 4);
  } else {
#pragma unroll
    for (int i = 0; i < 8; ++i) xx8[i] = 0.f;
  }
  const size_t ob = (size_t)m * C_ + c8;

  *(float4*)&t8[0] = *(const float4*)(tmk + c8);
  *(float4*)&t8[4] = *(const float4*)(tmk + c8 + 4);
  u16x8 o;
#pragma unroll
  for (int i = 0; i < 8; ++i) o[i] = f2bf(xv8[i] * t8[i] + xx8[i] * (1.f - t8[i]));
  *(u16x8*)(ok + ob) = o;

  *(float4*)&t8[0] = *(const float4*)(tmv + c8);
  *(float4*)&t8[4] = *(const float4*)(tmv + c8 + 4);
#pragma unroll
  for (int i = 0; i < 8; ++i) o[i] = f2bf(xv8[i] * t8[i] + xx8[i] * (1.f - t8[i]));
  *(u16x8*)(ov + ob) = o;

  *(float4*)&t8[0] = *(const float4*)(tmr + c8);
  *(float4*)&t8[4] = *(const float4*)(tmr + c8 + 4);
#pragma unroll
  for (int i = 0; i < 8; ++i) o[i] = f2bf(xv8[i] * t8[i] + xx8[i] * (1.f - t8[i]));
  *(u16x8*)(orr + ob) = o;
}

// ---------------------------------------------------------------------------
// Pipelined bf16 GEMM: out[m][n] = sum_k A[m][k] * W[n][k]
// BM=128 x BN=256 tile (round-14 swap: A-panel re-read 3x instead of 6x),
// BK=64, 8 waves (2M x 4N), wave tile 64x64. Triple-buffered LDS (144 KiB),
// depth-3 prefetch, counted vmcnt 12/6/0, raw s_barrier, XOR swizzle both
// sides, setprio around MFMA. Pipeline structure identical to round-7.
// ---------------------------------------------------------------------------
#define GBM 128
#define GBN 256
#define GBK 64
#define GNB ((M_ / GBM) * (C_ / GBN))  // 256*3 = 768
#define NT (C_ / GBK)                  // 12
#define BUFSZ 24576                    // shorts: A 8192 + B 16384
#define BOFF_B 8192

#define WAITV(n) asm volatile("s_waitcnt vmcnt(" #n ")" ::: "memory")

template <int OUT_BF16>
__global__ __launch_bounds__(512) void gemm8(const unsigned short* __restrict__ A,
                                             const unsigned short* __restrict__ W,
                                             void* __restrict__ outv) {
  __shared__ unsigned short lds[3 * BUFSZ];   // 147456 B

  int bid = (int)blockIdx.x;
  bid = (bid & 7) * (GNB / 8) + (bid >> 3);   // bijective: 768 % 8 == 0
  const int mt = bid / (C_ / GBN);            // 0..255
  const int nt = bid % (C_ / GBN);            // 0..2
  const int m0 = mt * GBM, n0 = nt * GBN;

  const int tid = threadIdx.x;
  const int lane = tid & 63;
  const int wv = tid >> 6;        // 0..7
  const int wm = wv >> 2;         // 0..1 over M=128 (64 rows each)
  const int wn = wv & 3;          // 0..3 over N=256 (64 cols each)

  // staging: pre-swizzled global source, linear LDS dest (rule #21).
  // each sweep covers 64 rows; A needs 2 sweeps (128), B needs 4 (256).
  const int l3 = lane >> 3;
  const int scol = (((lane & 7) ^ l3) << 3);   // element offset of 16B chunk
  const unsigned short* abase = A + (size_t)(m0 + wv * 8 + l3) * C_ + scol;
  const unsigned short* wbase = W + (size_t)(n0 + wv * 8 + l3) * C_ + scol;

#define STAGE(tt, bi)                                                         \
  {                                                                           \
    const int kk0_ = (tt) * GBK;                                              \
    _Pragma("unroll") for (int s_ = 0; s_ < 2; ++s_)                          \
        __builtin_amdgcn_global_load_lds(                                     \
            (g_void*)(abase + (size_t)s_ * 64 * C_ + kk0_),                   \
            (lds_void*)&lds[(bi) * BUFSZ + s_ * 4096 + wv * 512], 16, 0, 0);  \
    _Pragma("unroll") for (int s_ = 0; s_ < 4; ++s_)                          \
        __builtin_amdgcn_global_load_lds(                                     \
            (g_void*)(wbase + (size_t)s_ * 64 * C_ + kk0_),                   \
            (lds_void*)&lds[(bi) * BUFSZ + BOFF_B + s_ * 4096 + wv * 512],    \
            16, 0, 0);                                                        \
  }

  STAGE(0, 0);
  STAGE(1, 1);
  STAGE(2, 2);

  f32x4 acc[4][4] = {};
  const int arow = wm * 64 + (lane & 15);   // A rows 0..127
  const int brow = wn * 64 + (lane & 15);   // B rows 0..255

  int bufc = 0;
  for (int t = 0; t < NT; ++t) {
    if (t < NT - 2) { WAITV(12); }
    else if (t == NT - 2) { WAITV(6); }
    else { WAITV(0); }
    __builtin_amdgcn_s_barrier();
    __builtin_amdgcn_sched_barrier(0);

    const unsigned short* bufA = &lds[bufc * BUFSZ];
    const unsigned short* bufB = bufA + BOFF_B;

#pragma unroll
    for (int kk = 0; kk < 2; ++kk) {
      const int sw = ((((kk << 2) | (lane >> 4)) ^ (lane & 7)) << 3);
      bf16x8 af[4], bfv[4];
#pragma unroll
      for (int f = 0; f < 4; ++f)
        af[f] = *(const bf16x8*)&bufA[(arow + f * 16) * 64 + sw];
#pragma unroll
      for (int f = 0; f < 4; ++f)
        bfv[f] = *(const bf16x8*)&bufB[(brow + f * 16) * 64 + sw];
      __builtin_amdgcn_s_setprio(1);
#pragma unroll
      for (int i = 0; i < 4; ++i)
#pragma unroll
        for (int j = 0; j < 4; ++j)
          acc[i][j] = __builtin_amdgcn_mfma_f32_16x16x32_bf16(af[i], bfv[j], acc[i][j], 0, 0, 0);
      __builtin_amdgcn_s_setprio(0);
    }

    __builtin_amdgcn_s_barrier();
    __builtin_amdgcn_sched_barrier(0);
    if (t + 3 < NT) STAGE(t + 3, bufc);
    bufc = (bufc == 2) ? 0 : bufc + 1;
  }

  const int crow0 = m0 + wm * 64 + (lane >> 4) * 4;
  const int ccol0 = n0 + wn * 64 + (lane & 15);
  if (OUT_BF16) {
    unsigned short* out = (unsigned short*)outv;
#pragma unroll
    for (int i = 0; i < 4; ++i)
#pragma unroll
      for (int j = 0; j < 4; ++j)
#pragma unroll
        for (int r = 0; r < 4; ++r)
          out[(size_t)(crow0 + i * 16 + r) * C_ + ccol0 + j * 16] = f2bf(acc[i][j][r]);
  } else {
    float* out = (float*)outv;
#pragma unroll
    for (int i = 0; i < 4; ++i)
#pragma unroll
      for (int j = 0; j < 4; ++j)
#pragma unroll
        for (int r = 0; r < 4; ++r)
          out[(size_t)(crow0 + i * 16 + r) * C_ + ccol0 + j * 16] = acc[i][j][r];
  }
#undef STAGE
}

// ---------------------------------------------------------------------------
// WKV chunked associative scan -- STREAMING, 2 channels/thread (round-13
// proven math), reshaped to 512 threads: NCH=32 chunks x 16 channel-pairs.
// 8 waves/block, 12 KB LDS -> up to 4 blocks/CU; grid 768 -> ~3 blocks/CU
// resident (occupancy ~75% vs 31% at the 1024-thread shape).
// ---------------------------------------------------------------------------
#define NCH 32
#define CL  (T_ / NCH)   // 32
#define CPB 32           // channels per block

__global__ __launch_bounds__(512) void wkv_scan(const unsigned short* __restrict__ kin,
                                                const unsigned short* __restrict__ vin,
                                                const unsigned short* __restrict__ rin,
                                                const float* __restrict__ wdec,
                                                const float* __restrict__ ufirst,
                                                unsigned short* __restrict__ z) {
  __shared__ float ps[NCH][CPB], qs[NCH][CPB], os[NCH][CPB];

  const int b = blockIdx.x / (C_ / CPB);
  const int cg = blockIdx.x % (C_ / CPB);
  const int ci = threadIdx.x & 15;           // channel-pair index 0..15
  const int j = threadIdx.x >> 4;            // chunk 0..31
  const int c0 = cg * CPB + 2 * ci;
  const float w0 = wdec[c0], w1 = wdec[c0 + 1];
  const float u0 = ufirst[c0], u1 = ufirst[c0 + 1];
  const size_t base = ((size_t)b * T_ + (size_t)j * CL) * C_ + c0;

  // ---- phase 1: local chunk scan, packed streaming k,v ----
  float p0 = 0.f, q0 = 0.f, o0 = -1e38f;
  float p1 = 0.f, q1 = 0.f, o1 = -1e38f;
  {
    size_t idx = base;
#pragma unroll 4
    for (int t = 0; t < CL; ++t, idx += C_) {
      const unsigned int kk = *(const unsigned int*)(kin + idx);
      const unsigned int vv = *(const unsigned int*)(vin + idx);
      {
        const float kt = blo(kk), vt = blo(vv);
        const float d = (w0 + o0) - kt;
        const float e = __expf(-fabsf(d));
        const float A2 = (d < 0.f) ? e : 1.f;
        const float B2 = (d < 0.f) ? 1.f : e;
        p0 = A2 * p0 + B2 * vt;
        q0 = A2 * q0 + B2;
        o0 = fmaxf(w0 + o0, kt);
      }
      {
        const float kt = bhi(kk), vt = bhi(vv);
        const float d = (w1 + o1) - kt;
        const float e = __expf(-fabsf(d));
        const float A2 = (d < 0.f) ? e : 1.f;
        const float B2 = (d < 0.f) ? 1.f : e;
        p1 = A2 * p1 + B2 * vt;
        q1 = A2 * q1 + B2;
        o1 = fmaxf(w1 + o1, kt);
      }
    }
  }
  ps[j][2 * ci] = p0; qs[j][2 * ci] = q0; os[j][2 * ci] = o0;
  ps[j][2 * ci + 1] = p1; qs[j][2 * ci + 1] = q1; os[j][2 * ci + 1] = o1;
  __syncthreads();

  // ---- phase 2: Kogge-Stone inclusive scan over chunks (5 steps) ----
#pragma unroll
  for (int s = 1; s < NCH; s <<= 1) {
    float P0 = p0, Q0 = q0, O0 = o0, P1 = p1, Q1 = q1, O1 = o1;
    if (j >= s) {
      {
        const float lp = ps[j - s][2 * ci], lq = qs[j - s][2 * ci], lo = os[j - s][2 * ci];
        const float dsp = w0 * (float)(s * CL) + lo;
        const float dd = dsp - o0;
        const float e = __expf(-fabsf(dd));
        const float ea = (dd < 0.f) ? e : 1.f;
        const float eb = (dd < 0.f) ? 1.f : e;
        P0 = ea * lp + eb * p0;
        Q0 = ea * lq + eb * q0;
        O0 = fmaxf(dsp, o0);
      }
      {
        const float lp = ps[j - s][2 * ci + 1], lq = qs[j - s][2 * ci + 1], lo = os[j - s][2 * ci + 1];
        const float dsp = w1 * (float)(s * CL) + lo;
        const float dd = dsp - o1;
        const float e = __expf(-fabsf(dd));
        const float ea = (dd < 0.f) ? e : 1.f;
        const float eb = (dd < 0.f) ? 1.f : e;
        P1 = ea * lp + eb * p1;
        Q1 = ea * lq + eb * q1;
        O1 = fmaxf(dsp, o1);
      }
    }
    __syncthreads();
    p0 = P0; q0 = Q0; o0 = O0; p1 = P1; q1 = Q1; o1 = O1;
    ps[j][2 * ci] = p0; qs[j][2 * ci] = q0; os[j][2 * ci] = o0;
    ps[j][2 * ci + 1] = p1; qs[j][2 * ci + 1] = q1; os[j][2 * ci + 1] = o1;
    __syncthreads();
  }

  // ---- phase 3: re-scan with exclusive prefix, packed; emit z packed ----
  float pp0 = 0.f, qq0 = 0.f, oo0 = -1e38f;
  float pp1 = 0.f, qq1 = 0.f, oo1 = -1e38f;
  if (j > 0) {
    pp0 = ps[j - 1][2 * ci]; qq0 = qs[j - 1][2 * ci]; oo0 = os[j - 1][2 * ci];
    pp1 = ps[j - 1][2 * ci + 1]; qq1 = qs[j - 1][2 * ci + 1]; oo1 = os[j - 1][2 * ci + 1];
  }

  size_t idx = base;
#pragma unroll 4
  for (int t = 0; t < CL; ++t, idx += C_) {
    const unsigned int kk = *(const unsigned int*)(kin + idx);
    const unsigned int vv = *(const unsigned int*)(vin + idx);
    const unsigned int rr = *(const unsigned int*)(rin + idx);
    unsigned int zo;
    {
      const float kt = blo(kk), vt = blo(vv), rt = blo(rr);
      const float d1 = oo0 - (u0 + kt);
      const float e1 = __expf(-fabsf(d1));
      const float Ae = (d1 < 0.f) ? e1 : 1.f;
      const float Be = (d1 < 0.f) ? 1.f : e1;
      const float er = __expf(-rt);
      const float ysr = __fdividef(Ae * pp0 + Be * vt, (Ae * qq0 + Be) * (1.f + er));
      zo = (unsigned int)f2bf(ysr);
      const float d2 = (w0 + oo0) - kt;
      const float e2 = __expf(-fabsf(d2));
      const float A2 = (d2 < 0.f) ? e2 : 1.f;
      const float B2 = (d2 < 0.f) ? 1.f : e2;
      pp0 = A2 * pp0 + B2 * vt;
      qq0 = A2 * qq0 + B2;
      oo0 = fmaxf(w0 + oo0, kt);
    }
    {
      const float kt = bhi(kk), vt = bhi(vv), rt = bhi(rr);
      const float d1 = oo1 - (u1 + kt);
      const float e1 = __expf(-fabsf(d1));
      const float Ae = (d1 < 0.f) ? e1 : 1.f;
      const float Be = (d1 < 0.f) ? 1.f : e1;
      const float er = __expf(-rt);
      const float ysr = __fdividef(Ae * pp1 + Be * vt, (Ae * qq1 + Be) * (1.f + er));
      zo |= ((unsigned int)f2bf(ysr)) << 16;
      const float d2 = (w1 + oo1) - kt;
      const float e2 = __expf(-fabsf(d2));
      const float A2 = (d2 < 0.f) ? e2 : 1.f;
      const float B2 = (d2 < 0.f) ? 1.f : e2;
      pp1 = A2 * pp1 + B2 * vt;
      qq1 = A2 * qq1 + B2;
      oo1 = fmaxf(w1 + oo1, kt);
    }
    *(unsigned int*)(z + idx) = zo;
  }
}

// ---------------------------------------------------------------------------
extern "C" void kernel_launch(void* const* d_in, const int* in_sizes, int n_in,
                              void* d_out, int out_size, void* d_ws,
                              size_t ws_size, hipStream_t stream) {
  const float* x   = (const float*)d_in[0];
  const float* td  = (const float*)d_in[1];
  const float* tf  = (const float*)d_in[2];
  const float* tmk = (const float*)d_in[3];
  const float* tmv = (const float*)d_in[4];
  const float* tmr = (const float*)d_in[5];
  const float* Wk  = (const float*)d_in[6];
  const float* Wv  = (const float*)d_in[7];
  const float* Wr  = (const float*)d_in[8];
  const float* Wo  = (const float*)d_in[9];

  const size_t nW = (size_t)C_ * C_;
  const size_t nM = (size_t)M_ * C_;

  // ws (244.5 MiB): [wbk wbv wbr wbo][xk][xv][xr][kbuf][vbuf]  (all bf16)
  // rbuf lives in d_out (bf16; consumed by wkv before final GEMM overwrites)
  // z overlays xv (dead after gemm_v)
  unsigned short* wbk  = (unsigned short*)d_ws;
  unsigned short* wbv  = wbk + nW;
  unsigned short* wbr  = wbv + nW;
  unsigned short* wbo  = wbr + nW;
  unsigned short* xk   = wbo + nW;
  unsigned short* xv   = xk + nM;
  unsigned short* xr   = xv + nM;
  unsigned short* kbuf = xr + nM;
  unsigned short* vbuf = kbuf + nM;
  unsigned short* rbuf = (unsigned short*)d_out;
  unsigned short* zb   = xv;   // reuse

  prep<<<WBLK + MBLK, 256, 0, stream>>>(x, tmk, tmv, tmr, Wk, Wv, Wr, Wo,
                                        wbk, wbv, wbr, wbo, xk, xv, xr);

  gemm8<1><<<GNB, 512, 0, stream>>>(xk, wbk, kbuf);   // xk dies
  gemm8<1><<<GNB, 512, 0, stream>>>(xv, wbv, vbuf);   // xv dies
  gemm8<1><<<GNB, 512, 0, stream>>>(xr, wbr, rbuf);   // -> d_out (bf16)

  wkv_scan<<<B_ * (C_ / CPB), 512, 0, stream>>>(kbuf, vbuf, rbuf, td, tf, zb);

  gemm8<0><<<GNB, 512, 0, stream>>>(zb, wbo, d_out);  // f32 out
}

// Round 15
// 326.082 us; speedup vs baseline: 1.1208x; 1.1208x over previous
//
#include <hip/hip_runtime.h>
#include <math.h>

#define B_ 32
#define T_ 1024
#define C_ 768
#define M_ (B_ * T_)   // 32768

typedef __attribute__((ext_vector_type(8))) short bf16x8;
typedef __attribute__((ext_vector_type(4))) float f32x4;
typedef __attribute__((ext_vector_type(8))) unsigned short u16x8;
typedef __attribute__((address_space(1))) const void g_void;
typedef __attribute__((address_space(3))) void lds_void;

__device__ __forceinline__ unsigned short f2bf(float f) {
  union { float f; unsigned int u; } v; v.f = f;
  unsigned int u = v.u;
  u += 0x7fffu + ((u >> 16) & 1u);   // RNE
  return (unsigned short)(u >> 16);
}
__device__ __forceinline__ float b2f(unsigned short h) {
  union { unsigned int u; float f; } v; v.u = ((unsigned int)h) << 16;
  return v.f;
}
__device__ __forceinline__ float blo(unsigned int p) {   // low bf16 of packed pair
  union { unsigned int u; float f; } v; v.u = p << 16;
  return v.f;
}
__device__ __forceinline__ float bhi(unsigned int p) {   // high bf16 of packed pair
  union { unsigned int u; float f; } v; v.u = p & 0xffff0000u;
  return v.f;
}

// ---------------------------------------------------------------------------
// prep: fused {4x weight f32->bf16 convert} + {time-shift mix x->xk,xv,xr}
// ---------------------------------------------------------------------------
#define WPB 288                      // blocks per weight matrix
#define WBLK (4 * WPB)               // 1152
#define MBLK ((M_ * C_ / 8) / 256)   // 12288

__global__ __launch_bounds__(256) void prep(const float* __restrict__ x,
                                            const float* __restrict__ tmk,
                                            const float* __restrict__ tmv,
                                            const float* __restrict__ tmr,
                                            const float* __restrict__ Wk,
                                            const float* __restrict__ Wv,
                                            const float* __restrict__ Wr,
                                            const float* __restrict__ Wo,
                                            unsigned short* __restrict__ wbk,
                                            unsigned short* __restrict__ wbv,
                                            unsigned short* __restrict__ wbr,
                                            unsigned short* __restrict__ wbo,
                                            unsigned short* __restrict__ ok,
                                            unsigned short* __restrict__ ov,
                                            unsigned short* __restrict__ orr) {
  if (blockIdx.x < WBLK) {
    const int sel = blockIdx.x / WPB;              // 0..3
    const int wi = blockIdx.x % WPB;
    const float* src = (sel == 0) ? Wk : (sel == 1) ? Wv : (sel == 2) ? Wr : Wo;
    unsigned short* dst = (sel == 0) ? wbk : (sel == 1) ? wbv : (sel == 2) ? wbr : wbo;
    const int gi = wi * 256 + threadIdx.x;
    const float* p = src + (size_t)gi * 8;
    float v[8];
    *(float4*)&v[0] = *(const float4*)p;
    *(float4*)&v[4] = *(const float4*)(p + 4);
    u16x8 o;
#pragma unroll
    for (int i = 0; i < 8; ++i) o[i] = f2bf(v[i]);
    *(u16x8*)(dst + (size_t)gi * 8) = o;
    return;
  }

  const unsigned int gi = (blockIdx.x - WBLK) * 256u + threadIdx.x;
  const int m = gi / (C_ / 8);
  const int c8 = (gi % (C_ / 8)) * 8;
  const float* xp = x + (size_t)m * C_ + c8;
  float xv8[8], xx8[8], t8[8];
  *(float4*)&xv8[0] = *(const float4*)xp;
  *(float4*)&xv8[4] = *(const float4*)(xp + 4);
  if ((m & (T_ - 1)) != 0) {
    *(float4*)&xx8[0] = *(const float4*)(xp - C_);
    *(float4*)&xx8[4] = *(const float4*)(xp - C_ + 4);
  } else {
#pragma unroll
    for (int i = 0; i < 8; ++i) xx8[i] = 0.f;
  }
  const size_t ob = (size_t)m * C_ + c8;

  *(float4*)&t8[0] = *(const float4*)(tmk + c8);
  *(float4*)&t8[4] = *(const float4*)(tmk + c8 + 4);
  u16x8 o;
#pragma unroll
  for (int i = 0; i < 8; ++i) o[i] = f2bf(xv8[i] * t8[i] + xx8[i] * (1.f - t8[i]));
  *(u16x8*)(ok + ob) = o;

  *(float4*)&t8[0] = *(const float4*)(tmv + c8);
  *(float4*)&t8[4] = *(const float4*)(tmv + c8 + 4);
#pragma unroll
  for (int i = 0; i < 8; ++i) o[i] = f2bf(xv8[i] * t8[i] + xx8[i] * (1.f - t8[i]));
  *(u16x8*)(ov + ob) = o;

  *(float4*)&t8[0] = *(const float4*)(tmr + c8);
  *(float4*)&t8[4] = *(const float4*)(tmr + c8 + 4);
#pragma unroll
  for (int i = 0; i < 8; ++i) o[i] = f2bf(xv8[i] * t8[i] + xx8[i] * (1.f - t8[i]));
  *(u16x8*)(orr + ob) = o;
}

// ---------------------------------------------------------------------------
// Pipelined bf16 GEMM: out[m][n] = sum_k A[m][k] * W[n][k]
// Round-15: BM=128 x BN=128, BK=64, 4 waves (2x2, wave tile 64x64),
// DOUBLE-buffered LDS (64 KiB -> 2 blocks/CU so staging of one block
// overlaps MFMA of the other), counted vmcnt 8/0, raw s_barrier,
// XOR swizzle both sides (slot ^ row&7 invariant), setprio around MFMA.
// ---------------------------------------------------------------------------
#define GBM 128
#define GBN 128
#define GBK 64
#define GNB ((M_ / GBM) * (C_ / GBN))  // 256*6 = 1536
#define NT (C_ / GBK)                  // 12
#define BUFSZ 16384                    // shorts per buffer: A 8192 + B 8192
#define BOFF_B 8192

#define WAITV(n) asm volatile("s_waitcnt vmcnt(" #n ")" ::: "memory")

template <int OUT_BF16>
__global__ __launch_bounds__(256) void gemm8(const unsigned short* __restrict__ A,
                                             const unsigned short* __restrict__ W,
                                             void* __restrict__ outv) {
  __shared__ unsigned short lds[2 * BUFSZ];   // 65536 B -> 2 blocks/CU

  int bid = (int)blockIdx.x;
  bid = (bid & 7) * (GNB / 8) + (bid >> 3);   // bijective: 1536 % 8 == 0
  const int mt = bid / (C_ / GBN);            // 0..255
  const int nt = bid % (C_ / GBN);            // 0..5
  const int m0 = mt * GBM, n0 = nt * GBN;

  const int tid = threadIdx.x;
  const int lane = tid & 63;
  const int wv = tid >> 6;        // 0..3
  const int wm = wv >> 1;         // 0..1 over M=128
  const int wn = wv & 1;          // 0..1 over N=128

  // staging: pre-swizzled global source, linear LDS dest (rule #21).
  // per sweep: 4 waves x 8 rows = 32 rows; A needs 4 sweeps (128), B 4.
  const int l3 = lane >> 3;
  const int scol = (((lane & 7) ^ l3) << 3);   // element offset of 16B chunk
  const unsigned short* abase = A + (size_t)(m0 + wv * 8 + l3) * C_ + scol;
  const unsigned short* wbase = W + (size_t)(n0 + wv * 8 + l3) * C_ + scol;

#define STAGE(tt, bi)                                                         \
  {                                                                           \
    const int kk0_ = (tt) * GBK;                                              \
    _Pragma("unroll") for (int s_ = 0; s_ < 4; ++s_)                          \
        __builtin_amdgcn_global_load_lds(                                     \
            (g_void*)(abase + (size_t)s_ * 32 * C_ + kk0_),                   \
            (lds_void*)&lds[(bi) * BUFSZ + s_ * 2048 + wv * 512], 16, 0, 0);  \
    _Pragma("unroll") for (int s_ = 0; s_ < 4; ++s_)                          \
        __builtin_amdgcn_global_load_lds(                                     \
            (g_void*)(wbase + (size_t)s_ * 32 * C_ + kk0_),                   \
            (lds_void*)&lds[(bi) * BUFSZ + BOFF_B + s_ * 2048 + wv * 512],    \
            16, 0, 0);                                                        \
  }

  STAGE(0, 0);
  STAGE(1, 1);

  f32x4 acc[4][4] = {};
  const int arow = wm * 64 + (lane & 15);   // A rows 0..127
  const int brow = wn * 64 + (lane & 15);   // B rows 0..127

  for (int t = 0; t < NT; ++t) {
    if (t < NT - 1) { WAITV(8); }   // tile t's 8 loads retired; t+1 in flight
    else { WAITV(0); }
    __builtin_amdgcn_s_barrier();
    __builtin_amdgcn_sched_barrier(0);

    const unsigned short* bufA = &lds[(t & 1) * BUFSZ];
    const unsigned short* bufB = bufA + BOFF_B;

#pragma unroll
    for (int kk = 0; kk < 2; ++kk) {
      const int sw = ((((kk << 2) | (lane >> 4)) ^ (lane & 7)) << 3);
      bf16x8 af[4], bfv[4];
#pragma unroll
      for (int f = 0; f < 4; ++f)
        af[f] = *(const bf16x8*)&bufA[(arow + f * 16) * 64 + sw];
#pragma unroll
      for (int f = 0; f < 4; ++f)
        bfv[f] = *(const bf16x8*)&bufB[(brow + f * 16) * 64 + sw];
      __builtin_amdgcn_s_setprio(1);
#pragma unroll
      for (int i = 0; i < 4; ++i)
#pragma unroll
        for (int j = 0; j < 4; ++j)
          acc[i][j] = __builtin_amdgcn_mfma_f32_16x16x32_bf16(af[i], bfv[j], acc[i][j], 0, 0, 0);
      __builtin_amdgcn_s_setprio(0);
    }

    __builtin_amdgcn_s_barrier();          // all reads of buf[t&1] done
    __builtin_amdgcn_sched_barrier(0);
    if (t + 2 < NT) STAGE(t + 2, t & 1);   // refill the buffer just freed
  }

  const int crow0 = m0 + wm * 64 + (lane >> 4) * 4;
  const int ccol0 = n0 + wn * 64 + (lane & 15);
  if (OUT_BF16) {
    unsigned short* out = (unsigned short*)outv;
#pragma unroll
    for (int i = 0; i < 4; ++i)
#pragma unroll
      for (int j = 0; j < 4; ++j)
#pragma unroll
        for (int r = 0; r < 4; ++r)
          out[(size_t)(crow0 + i * 16 + r) * C_ + ccol0 + j * 16] = f2bf(acc[i][j][r]);
  } else {
    float* out = (float*)outv;
#pragma unroll
    for (int i = 0; i < 4; ++i)
#pragma unroll
      for (int j = 0; j < 4; ++j)
#pragma unroll
        for (int r = 0; r < 4; ++r)
          out[(size_t)(crow0 + i * 16 + r) * C_ + ccol0 + j * 16] = acc[i][j][r];
  }
#undef STAGE
}

// ---------------------------------------------------------------------------
// WKV chunked associative scan -- round-13 proven form (79.5 us, FETCH
// 122 MB): 1024 threads, 64 channels/block (2/thread, packed 4B loads ->
// 128B wave segments; r14 showed 32-ch blocks double HBM fetch), NCH=32.
// ---------------------------------------------------------------------------
#define NCH 32
#define CL  (T_ / NCH)   // 32

__global__ __launch_bounds__(1024) void wkv_scan(const unsigned short* __restrict__ kin,
                                                 const unsigned short* __restrict__ vin,
                                                 const unsigned short* __restrict__ rin,
                                                 const float* __restrict__ wdec,
                                                 const float* __restrict__ ufirst,
                                                 unsigned short* __restrict__ z) {
  __shared__ float ps[NCH][64], qs[NCH][64], os[NCH][64];

  const int b = blockIdx.x / (C_ / 64);
  const int cg = blockIdx.x % (C_ / 64);
  const int ci = threadIdx.x & 31;           // channel-pair index
  const int j = threadIdx.x >> 5;            // chunk 0..31
  const int c0 = cg * 64 + 2 * ci;
  const float w0 = wdec[c0], w1 = wdec[c0 + 1];
  const float u0 = ufirst[c0], u1 = ufirst[c0 + 1];
  const size_t base = ((size_t)b * T_ + (size_t)j * CL) * C_ + c0;

  // ---- phase 1: local chunk scan, packed streaming k,v ----
  float p0 = 0.f, q0 = 0.f, o0 = -1e38f;
  float p1 = 0.f, q1 = 0.f, o1 = -1e38f;
  {
    size_t idx = base;
#pragma unroll 4
    for (int t = 0; t < CL; ++t, idx += C_) {
      const unsigned int kk = *(const unsigned int*)(kin + idx);
      const unsigned int vv = *(const unsigned int*)(vin + idx);
      {
        const float kt = blo(kk), vt = blo(vv);
        const float d = (w0 + o0) - kt;
        const float e = __expf(-fabsf(d));
        const float A2 = (d < 0.f) ? e : 1.f;
        const float B2 = (d < 0.f) ? 1.f : e;
        p0 = A2 * p0 + B2 * vt;
        q0 = A2 * q0 + B2;
        o0 = fmaxf(w0 + o0, kt);
      }
      {
        const float kt = bhi(kk), vt = bhi(vv);
        const float d = (w1 + o1) - kt;
        const float e = __expf(-fabsf(d));
        const float A2 = (d < 0.f) ? e : 1.f;
        const float B2 = (d < 0.f) ? 1.f : e;
        p1 = A2 * p1 + B2 * vt;
        q1 = A2 * q1 + B2;
        o1 = fmaxf(w1 + o1, kt);
      }
    }
  }
  ps[j][2 * ci] = p0; qs[j][2 * ci] = q0; os[j][2 * ci] = o0;
  ps[j][2 * ci + 1] = p1; qs[j][2 * ci + 1] = q1; os[j][2 * ci + 1] = o1;
  __syncthreads();

  // ---- phase 2: Kogge-Stone inclusive scan over chunks (5 steps) ----
#pragma unroll
  for (int s = 1; s < NCH; s <<= 1) {
    float P0 = p0, Q0 = q0, O0 = o0, P1 = p1, Q1 = q1, O1 = o1;
    if (j >= s) {
      {
        const float lp = ps[j - s][2 * ci], lq = qs[j - s][2 * ci], lo = os[j - s][2 * ci];
        const float dsp = w0 * (float)(s * CL) + lo;
        const float dd = dsp - o0;
        const float e = __expf(-fabsf(dd));
        const float ea = (dd < 0.f) ? e : 1.f;
        const float eb = (dd < 0.f) ? 1.f : e;
        P0 = ea * lp + eb * p0;
        Q0 = ea * lq + eb * q0;
        O0 = fmaxf(dsp, o0);
      }
      {
        const float lp = ps[j - s][2 * ci + 1], lq = qs[j - s][2 * ci + 1], lo = os[j - s][2 * ci + 1];
        const float dsp = w1 * (float)(s * CL) + lo;
        const float dd = dsp - o1;
        const float e = __expf(-fabsf(dd));
        const float ea = (dd < 0.f) ? e : 1.f;
        const float eb = (dd < 0.f) ? 1.f : e;
        P1 = ea * lp + eb * p1;
        Q1 = ea * lq + eb * q1;
        O1 = fmaxf(dsp, o1);
      }
    }
    __syncthreads();
    p0 = P0; q0 = Q0; o0 = O0; p1 = P1; q1 = Q1; o1 = O1;
    ps[j][2 * ci] = p0; qs[j][2 * ci] = q0; os[j][2 * ci] = o0;
    ps[j][2 * ci + 1] = p1; qs[j][2 * ci + 1] = q1; os[j][2 * ci + 1] = o1;
    __syncthreads();
  }

  // ---- phase 3: re-scan with exclusive prefix, packed; emit z packed ----
  float pp0 = 0.f, qq0 = 0.f, oo0 = -1e38f;
  float pp1 = 0.f, qq1 = 0.f, oo1 = -1e38f;
  if (j > 0) {
    pp0 = ps[j - 1][2 * ci]; qq0 = qs[j - 1][2 * ci]; oo0 = os[j - 1][2 * ci];
    pp1 = ps[j - 1][2 * ci + 1]; qq1 = qs[j - 1][2 * ci + 1]; oo1 = os[j - 1][2 * ci + 1];
  }

  size_t idx = base;
#pragma unroll 4
  for (int t = 0; t < CL; ++t, idx += C_) {
    const unsigned int kk = *(const unsigned int*)(kin + idx);
    const unsigned int vv = *(const unsigned int*)(vin + idx);
    const unsigned int rr = *(const unsigned int*)(rin + idx);
    unsigned int zo;
    {
      const float kt = blo(kk), vt = blo(vv), rt = blo(rr);
      const float d1 = oo0 - (u0 + kt);
      const float e1 = __expf(-fabsf(d1));
      const float Ae = (d1 < 0.f) ? e1 : 1.f;
      const float Be = (d1 < 0.f) ? 1.f : e1;
      const float er = __expf(-rt);
      const float ysr = __fdividef(Ae * pp0 + Be * vt, (Ae * qq0 + Be) * (1.f + er));
      zo = (unsigned int)f2bf(ysr);
      const float d2 = (w0 + oo0) - kt;
      const float e2 = __expf(-fabsf(d2));
      const float A2 = (d2 < 0.f) ? e2 : 1.f;
      const float B2 = (d2 < 0.f) ? 1.f : e2;
      pp0 = A2 * pp0 + B2 * vt;
      qq0 = A2 * qq0 + B2;
      oo0 = fmaxf(w0 + oo0, kt);
    }
    {
      const float kt = bhi(kk), vt = bhi(vv), rt = bhi(rr);
      const float d1 = oo1 - (u1 + kt);
      const float e1 = __expf(-fabsf(d1));
      const float Ae = (d1 < 0.f) ? e1 : 1.f;
      const float Be = (d1 < 0.f) ? 1.f : e1;
      const float er = __expf(-rt);
      const float ysr = __fdividef(Ae * pp1 + Be * vt, (Ae * qq1 + Be) * (1.f + er));
      zo |= ((unsigned int)f2bf(ysr)) << 16;
      const float d2 = (w1 + oo1) - kt;
      const float e2 = __expf(-fabsf(d2));
      const float A2 = (d2 < 0.f) ? e2 : 1.f;
      const float B2 = (d2 < 0.f) ? 1.f : e2;
      pp1 = A2 * pp1 + B2 * vt;
      qq1 = A2 * qq1 + B2;
      oo1 = fmaxf(w1 + oo1, kt);
    }
    *(unsigned int*)(z + idx) = zo;
  }
}

// ---------------------------------------------------------------------------
extern "C" void kernel_launch(void* const* d_in, const int* in_sizes, int n_in,
                              void* d_out, int out_size, void* d_ws,
                              size_t ws_size, hipStream_t stream) {
  const float* x   = (const float*)d_in[0];
  const float* td  = (const float*)d_in[1];
  const float* tf  = (const float*)d_in[2];
  const float* tmk = (const float*)d_in[3];
  const float* tmv = (const float*)d_in[4];
  const float* tmr = (const float*)d_in[5];
  const float* Wk  = (const float*)d_in[6];
  const float* Wv  = (const float*)d_in[7];
  const float* Wr  = (const float*)d_in[8];
  const float* Wo  = (const float*)d_in[9];

  const size_t nW = (size_t)C_ * C_;
  const size_t nM = (size_t)M_ * C_;

  // ws (244.5 MiB): [wbk wbv wbr wbo][xk][xv][xr][kbuf][vbuf]  (all bf16)
  // rbuf lives in d_out (bf16; consumed by wkv before final GEMM overwrites)
  // z overlays xv (dead after gemm_v)
  unsigned short* wbk  = (unsigned short*)d_ws;
  unsigned short* wbv  = wbk + nW;
  unsigned short* wbr  = wbv + nW;
  unsigned short* wbo  = wbr + nW;
  unsigned short* xk   = wbo + nW;
  unsigned short* xv   = xk + nM;
  unsigned short* xr   = xv + nM;
  unsigned short* kbuf = xr + nM;
  unsigned short* vbuf = kbuf + nM;
  unsigned short* rbuf = (unsigned short*)d_out;
  unsigned short* zb   = xv;   // reuse

  prep<<<WBLK + MBLK, 256, 0, stream>>>(x, tmk, tmv, tmr, Wk, Wv, Wr, Wo,
                                        wbk, wbv, wbr, wbo, xk, xv, xr);

  gemm8<1><<<GNB, 256, 0, stream>>>(xk, wbk, kbuf);   // xk dies
  gemm8<1><<<GNB, 256, 0, stream>>>(xv, wbv, vbuf);   // xv dies
  gemm8<1><<<GNB, 256, 0, stream>>>(xr, wbr, rbuf);   // -> d_out (bf16)

  wkv_scan<<<B_ * (C_ / 64), 1024, 0, stream>>>(kbuf, vbuf, rbuf, td, tf, zb);

  gemm8<0><<<GNB, 256, 0, stream>>>(zb, wbo, d_out);  // f32 out
}

// Round 16
// 324.270 us; speedup vs baseline: 1.1271x; 1.0056x over previous
//
#include <hip/hip_runtime.h>
#include <math.h>

#define B_ 32
#define T_ 1024
#define C_ 768
#define M_ (B_ * T_)   // 32768

typedef __attribute__((ext_vector_type(8))) short bf16x8;
typedef __attribute__((ext_vector_type(4))) float f32x4;
typedef __attribute__((ext_vector_type(8))) unsigned short u16x8;
typedef __attribute__((address_space(1))) const void g_void;
typedef __attribute__((address_space(3))) void lds_void;

__device__ __forceinline__ unsigned short f2bf(float f) {
  union { float f; unsigned int u; } v; v.f = f;
  unsigned int u = v.u;
  u += 0x7fffu + ((u >> 16) & 1u);   // RNE
  return (unsigned short)(u >> 16);
}
__device__ __forceinline__ float b2f(unsigned short h) {
  union { unsigned int u; float f; } v; v.u = ((unsigned int)h) << 16;
  return v.f;
}
__device__ __forceinline__ float blo(unsigned int p) {   // low bf16 of packed pair
  union { unsigned int u; float f; } v; v.u = p << 16;
  return v.f;
}
__device__ __forceinline__ float bhi(unsigned int p) {   // high bf16 of packed pair
  union { unsigned int u; float f; } v; v.u = p & 0xffff0000u;
  return v.f;
}

// ---------------------------------------------------------------------------
// prep: fused {4x weight f32->bf16 convert} + {time-shift mix x->xk,xv,xr}
// ---------------------------------------------------------------------------
#define WPB 288                      // blocks per weight matrix
#define WBLK (4 * WPB)               // 1152
#define MBLK ((M_ * C_ / 8) / 256)   // 12288

__global__ __launch_bounds__(256) void prep(const float* __restrict__ x,
                                            const float* __restrict__ tmk,
                                            const float* __restrict__ tmv,
                                            const float* __restrict__ tmr,
                                            const float* __restrict__ Wk,
                                            const float* __restrict__ Wv,
                                            const float* __restrict__ Wr,
                                            const float* __restrict__ Wo,
                                            unsigned short* __restrict__ wbk,
                                            unsigned short* __restrict__ wbv,
                                            unsigned short* __restrict__ wbr,
                                            unsigned short* __restrict__ wbo,
                                            unsigned short* __restrict__ ok,
                                            unsigned short* __restrict__ ov,
                                            unsigned short* __restrict__ orr) {
  if (blockIdx.x < WBLK) {
    const int sel = blockIdx.x / WPB;              // 0..3
    const int wi = blockIdx.x % WPB;
    const float* src = (sel == 0) ? Wk : (sel == 1) ? Wv : (sel == 2) ? Wr : Wo;
    unsigned short* dst = (sel == 0) ? wbk : (sel == 1) ? wbv : (sel == 2) ? wbr : wbo;
    const int gi = wi * 256 + threadIdx.x;
    const float* p = src + (size_t)gi * 8;
    float v[8];
    *(float4*)&v[0] = *(const float4*)p;
    *(float4*)&v[4] = *(const float4*)(p + 4);
    u16x8 o;
#pragma unroll
    for (int i = 0; i < 8; ++i) o[i] = f2bf(v[i]);
    *(u16x8*)(dst + (size_t)gi * 8) = o;
    return;
  }

  const unsigned int gi = (blockIdx.x - WBLK) * 256u + threadIdx.x;
  const int m = gi / (C_ / 8);
  const int c8 = (gi % (C_ / 8)) * 8;
  const float* xp = x + (size_t)m * C_ + c8;
  float xv8[8], xx8[8], t8[8];
  *(float4*)&xv8[0] = *(const float4*)xp;
  *(float4*)&xv8[4] = *(const float4*)(xp + 4);
  if ((m & (T_ - 1)) != 0) {
    *(float4*)&xx8[0] = *(const float4*)(xp - C_);
    *(float4*)&xx8[4] = *(const float4*)(xp - C_ + 4);
  } else {
#pragma unroll
    for (int i = 0; i < 8; ++i) xx8[i] = 0.f;
  }
  const size_t ob = (size_t)m * C_ + c8;

  *(float4*)&t8[0] = *(const float4*)(tmk + c8);
  *(float4*)&t8[4] = *(const float4*)(tmk + c8 + 4);
  u16x8 o;
#pragma unroll
  for (int i = 0; i < 8; ++i) o[i] = f2bf(xv8[i] * t8[i] + xx8[i] * (1.f - t8[i]));
  *(u16x8*)(ok + ob) = o;

  *(float4*)&t8[0] = *(const float4*)(tmv + c8);
  *(float4*)&t8[4] = *(const float4*)(tmv + c8 + 4);
#pragma unroll
  for (int i = 0; i < 8; ++i) o[i] = f2bf(xv8[i] * t8[i] + xx8[i] * (1.f - t8[i]));
  *(u16x8*)(ov + ob) = o;

  *(float4*)&t8[0] = *(const float4*)(tmr + c8);
  *(float4*)&t8[4] = *(const float4*)(tmr + c8 + 4);
#pragma unroll
  for (int i = 0; i < 8; ++i) o[i] = f2bf(xv8[i] * t8[i] + xx8[i] * (1.f - t8[i]));
  *(u16x8*)(orr + ob) = o;
}

// ---------------------------------------------------------------------------
// Pipelined bf16 GEMM (round-15 proven): BM=128 x BN=128, BK=64, 4 waves,
// double-buffered LDS (64 KiB -> 2 blocks/CU), counted vmcnt 8/0,
// raw s_barrier, XOR swizzle both sides, setprio around MFMA.
// ---------------------------------------------------------------------------
#define GBM 128
#define GBN 128
#define GBK 64
#define GNB ((M_ / GBM) * (C_ / GBN))  // 1536
#define NT (C_ / GBK)                  // 12
#define BUFSZ 16384
#define BOFF_B 8192

#define WAITV(n) asm volatile("s_waitcnt vmcnt(" #n ")" ::: "memory")

template <int OUT_BF16>
__global__ __launch_bounds__(256) void gemm8(const unsigned short* __restrict__ A,
                                             const unsigned short* __restrict__ W,
                                             void* __restrict__ outv) {
  __shared__ unsigned short lds[2 * BUFSZ];

  int bid = (int)blockIdx.x;
  bid = (bid & 7) * (GNB / 8) + (bid >> 3);
  const int mt = bid / (C_ / GBN);
  const int nt = bid % (C_ / GBN);
  const int m0 = mt * GBM, n0 = nt * GBN;

  const int tid = threadIdx.x;
  const int lane = tid & 63;
  const int wv = tid >> 6;
  const int wm = wv >> 1;
  const int wn = wv & 1;

  const int l3 = lane >> 3;
  const int scol = (((lane & 7) ^ l3) << 3);
  const unsigned short* abase = A + (size_t)(m0 + wv * 8 + l3) * C_ + scol;
  const unsigned short* wbase = W + (size_t)(n0 + wv * 8 + l3) * C_ + scol;

#define STAGE(tt, bi)                                                         \
  {                                                                           \
    const int kk0_ = (tt) * GBK;                                              \
    _Pragma("unroll") for (int s_ = 0; s_ < 4; ++s_)                          \
        __builtin_amdgcn_global_load_lds(                                     \
            (g_void*)(abase + (size_t)s_ * 32 * C_ + kk0_),                   \
            (lds_void*)&lds[(bi) * BUFSZ + s_ * 2048 + wv * 512], 16, 0, 0);  \
    _Pragma("unroll") for (int s_ = 0; s_ < 4; ++s_)                          \
        __builtin_amdgcn_global_load_lds(                                     \
            (g_void*)(wbase + (size_t)s_ * 32 * C_ + kk0_),                   \
            (lds_void*)&lds[(bi) * BUFSZ + BOFF_B + s_ * 2048 + wv * 512],    \
            16, 0, 0);                                                        \
  }

  STAGE(0, 0);
  STAGE(1, 1);

  f32x4 acc[4][4] = {};
  const int arow = wm * 64 + (lane & 15);
  const int brow = wn * 64 + (lane & 15);

  for (int t = 0; t < NT; ++t) {
    if (t < NT - 1) { WAITV(8); }
    else { WAITV(0); }
    __builtin_amdgcn_s_barrier();
    __builtin_amdgcn_sched_barrier(0);

    const unsigned short* bufA = &lds[(t & 1) * BUFSZ];
    const unsigned short* bufB = bufA + BOFF_B;

#pragma unroll
    for (int kk = 0; kk < 2; ++kk) {
      const int sw = ((((kk << 2) | (lane >> 4)) ^ (lane & 7)) << 3);
      bf16x8 af[4], bfv[4];
#pragma unroll
      for (int f = 0; f < 4; ++f)
        af[f] = *(const bf16x8*)&bufA[(arow + f * 16) * 64 + sw];
#pragma unroll
      for (int f = 0; f < 4; ++f)
        bfv[f] = *(const bf16x8*)&bufB[(brow + f * 16) * 64 + sw];
      __builtin_amdgcn_s_setprio(1);
#pragma unroll
      for (int i = 0; i < 4; ++i)
#pragma unroll
        for (int j = 0; j < 4; ++j)
          acc[i][j] = __builtin_amdgcn_mfma_f32_16x16x32_bf16(af[i], bfv[j], acc[i][j], 0, 0, 0);
      __builtin_amdgcn_s_setprio(0);
    }

    __builtin_amdgcn_s_barrier();
    __builtin_amdgcn_sched_barrier(0);
    if (t + 2 < NT) STAGE(t + 2, t & 1);
  }

  const int crow0 = m0 + wm * 64 + (lane >> 4) * 4;
  const int ccol0 = n0 + wn * 64 + (lane & 15);
  if (OUT_BF16) {
    unsigned short* out = (unsigned short*)outv;
#pragma unroll
    for (int i = 0; i < 4; ++i)
#pragma unroll
      for (int j = 0; j < 4; ++j)
#pragma unroll
        for (int r = 0; r < 4; ++r)
          out[(size_t)(crow0 + i * 16 + r) * C_ + ccol0 + j * 16] = f2bf(acc[i][j][r]);
  } else {
    float* out = (float*)outv;
#pragma unroll
    for (int i = 0; i < 4; ++i)
#pragma unroll
      for (int j = 0; j < 4; ++j)
#pragma unroll
        for (int r = 0; r < 4; ++r)
          out[(size_t)(crow0 + i * 16 + r) * C_ + ccol0 + j * 16] = acc[i][j][r];
  }
#undef STAGE
}

// ---------------------------------------------------------------------------
// WKV chunked associative scan -- round-16: 512 threads, 64 channels/block
// (2/thread packed -> 128B wave segments, r13-proven), 2 CHUNKS PER THREAD
// (jA = j, jB = j+16): two independent serial scan chains per thread give
// 2-way ILP on the exp-latency chain; 8-wave blocks pack CUs uniformly.
// ---------------------------------------------------------------------------
#define NCH 32
#define CL  (T_ / NCH)   // 32

#define SCAN_STEP(w_, kt, vt, p_, q_, o_)                    \
  {                                                          \
    const float d_ = (w_ + o_) - (kt);                       \
    const float e_ = __expf(-fabsf(d_));                     \
    const float A_ = (d_ < 0.f) ? e_ : 1.f;                  \
    const float Bc_ = (d_ < 0.f) ? 1.f : e_;                 \
    p_ = A_ * p_ + Bc_ * (vt);                               \
    q_ = A_ * q_ + Bc_;                                      \
    o_ = fmaxf(w_ + o_, (kt));                               \
  }

#define KS_COMBINE(w_, lp_, lq_, lo_, p_, q_, o_, span_)     \
  {                                                          \
    const float dsp_ = (w_) * (float)(span_) + (lo_);        \
    const float dd_ = dsp_ - o_;                             \
    const float e_ = __expf(-fabsf(dd_));                    \
    const float ea_ = (dd_ < 0.f) ? e_ : 1.f;                \
    const float eb_ = (dd_ < 0.f) ? 1.f : e_;                \
    p_ = ea_ * (lp_) + eb_ * p_;                             \
    q_ = ea_ * (lq_) + eb_ * q_;                             \
    o_ = fmaxf(dsp_, o_);                                    \
  }

#define Y_STEP(w_, u_, kt, vt, rt, pp_, qq_, oo_, zres_)     \
  {                                                          \
    const float d1_ = oo_ - ((u_) + (kt));                   \
    const float e1_ = __expf(-fabsf(d1_));                   \
    const float Ae_ = (d1_ < 0.f) ? e1_ : 1.f;               \
    const float Be_ = (d1_ < 0.f) ? 1.f : e1_;               \
    const float er_ = __expf(-(rt));                         \
    zres_ = __fdividef(Ae_ * pp_ + Be_ * (vt),               \
                       (Ae_ * qq_ + Be_) * (1.f + er_));     \
    SCAN_STEP(w_, kt, vt, pp_, qq_, oo_)                     \
  }

__global__ __launch_bounds__(512) void wkv_scan(const unsigned short* __restrict__ kin,
                                                const unsigned short* __restrict__ vin,
                                                const unsigned short* __restrict__ rin,
                                                const float* __restrict__ wdec,
                                                const float* __restrict__ ufirst,
                                                unsigned short* __restrict__ z) {
  __shared__ float ps[NCH][64], qs[NCH][64], os[NCH][64];

  const int b = blockIdx.x / (C_ / 64);
  const int cg = blockIdx.x % (C_ / 64);
  const int ci = threadIdx.x & 31;           // channel-pair index 0..31
  const int j = threadIdx.x >> 5;            // 0..15
  const int jA = j, jB = j + 16;             // this thread's two chunks
  const int c0 = cg * 64 + 2 * ci;
  const float w0 = wdec[c0], w1 = wdec[c0 + 1];
  const float u0 = ufirst[c0], u1 = ufirst[c0 + 1];
  const size_t baseA = ((size_t)b * T_ + (size_t)jA * CL) * C_ + c0;
  const size_t baseB = ((size_t)b * T_ + (size_t)jB * CL) * C_ + c0;

  // ---- phase 1: two independent local chunk scans (2-way ILP) ----
  float Ap0 = 0.f, Aq0 = 0.f, Ao0 = -1e38f, Ap1 = 0.f, Aq1 = 0.f, Ao1 = -1e38f;
  float Bp0 = 0.f, Bq0 = 0.f, Bo0 = -1e38f, Bp1 = 0.f, Bq1 = 0.f, Bo1 = -1e38f;
  {
    size_t ia = baseA, ib = baseB;
#pragma unroll 4
    for (int t = 0; t < CL; ++t, ia += C_, ib += C_) {
      const unsigned int kA = *(const unsigned int*)(kin + ia);
      const unsigned int vA = *(const unsigned int*)(vin + ia);
      const unsigned int kB = *(const unsigned int*)(kin + ib);
      const unsigned int vB = *(const unsigned int*)(vin + ib);
      SCAN_STEP(w0, blo(kA), blo(vA), Ap0, Aq0, Ao0)
      SCAN_STEP(w1, bhi(kA), bhi(vA), Ap1, Aq1, Ao1)
      SCAN_STEP(w0, blo(kB), blo(vB), Bp0, Bq0, Bo0)
      SCAN_STEP(w1, bhi(kB), bhi(vB), Bp1, Bq1, Bo1)
    }
  }
  ps[jA][2 * ci] = Ap0; qs[jA][2 * ci] = Aq0; os[jA][2 * ci] = Ao0;
  ps[jA][2 * ci + 1] = Ap1; qs[jA][2 * ci + 1] = Aq1; os[jA][2 * ci + 1] = Ao1;
  ps[jB][2 * ci] = Bp0; qs[jB][2 * ci] = Bq0; os[jB][2 * ci] = Bo0;
  ps[jB][2 * ci + 1] = Bp1; qs[jB][2 * ci + 1] = Bq1; os[jB][2 * ci + 1] = Bo1;
  __syncthreads();

  // ---- phase 2: Kogge-Stone inclusive scan over 32 chunks (5 steps),
  //      each thread updates both its chunks ----
#pragma unroll
  for (int s = 1; s < NCH; s <<= 1) {
    float tAp0 = Ap0, tAq0 = Aq0, tAo0 = Ao0, tAp1 = Ap1, tAq1 = Aq1, tAo1 = Ao1;
    float tBp0 = Bp0, tBq0 = Bq0, tBo0 = Bo0, tBp1 = Bp1, tBq1 = Bq1, tBo1 = Bo1;
    if (jA >= s) {
      KS_COMBINE(w0, ps[jA - s][2 * ci], qs[jA - s][2 * ci], os[jA - s][2 * ci],
                 tAp0, tAq0, tAo0, s * CL)
      KS_COMBINE(w1, ps[jA - s][2 * ci + 1], qs[jA - s][2 * ci + 1], os[jA - s][2 * ci + 1],
                 tAp1, tAq1, tAo1, s * CL)
    }
    // jB = j+16 >= 16 >= s always
    KS_COMBINE(w0, ps[jB - s][2 * ci], qs[jB - s][2 * ci], os[jB - s][2 * ci],
               tBp0, tBq0, tBo0, s * CL)
    KS_COMBINE(w1, ps[jB - s][2 * ci + 1], qs[jB - s][2 * ci + 1], os[jB - s][2 * ci + 1],
               tBp1, tBq1, tBo1, s * CL)
    __syncthreads();
    Ap0 = tAp0; Aq0 = tAq0; Ao0 = tAo0; Ap1 = tAp1; Aq1 = tAq1; Ao1 = tAo1;
    Bp0 = tBp0; Bq0 = tBq0; Bo0 = tBo0; Bp1 = tBp1; Bq1 = tBq1; Bo1 = tBo1;
    ps[jA][2 * ci] = Ap0; qs[jA][2 * ci] = Aq0; os[jA][2 * ci] = Ao0;
    ps[jA][2 * ci + 1] = Ap1; qs[jA][2 * ci + 1] = Aq1; os[jA][2 * ci + 1] = Ao1;
    ps[jB][2 * ci] = Bp0; qs[jB][2 * ci] = Bq0; os[jB][2 * ci] = Bo0;
    ps[jB][2 * ci + 1] = Bp1; qs[jB][2 * ci + 1] = Bq1; os[jB][2 * ci + 1] = Bo1;
    __syncthreads();
  }

  // ---- phase 3: re-scan both chunks with exclusive prefixes (2-way ILP) ----
  float pA0 = 0.f, qA0 = 0.f, oA0 = -1e38f, pA1 = 0.f, qA1 = 0.f, oA1 = -1e38f;
  if (j > 0) {
    pA0 = ps[jA - 1][2 * ci]; qA0 = qs[jA - 1][2 * ci]; oA0 = os[jA - 1][2 * ci];
    pA1 = ps[jA - 1][2 * ci + 1]; qA1 = qs[jA - 1][2 * ci + 1]; oA1 = os[jA - 1][2 * ci + 1];
  }
  float pB0 = ps[jB - 1][2 * ci], qB0 = qs[jB - 1][2 * ci], oB0 = os[jB - 1][2 * ci];
  float pB1 = ps[jB - 1][2 * ci + 1], qB1 = qs[jB - 1][2 * ci + 1], oB1 = os[jB - 1][2 * ci + 1];

  {
    size_t ia = baseA, ib = baseB;
#pragma unroll 4
    for (int t = 0; t < CL; ++t, ia += C_, ib += C_) {
      const unsigned int kA = *(const unsigned int*)(kin + ia);
      const unsigned int vA = *(const unsigned int*)(vin + ia);
      const unsigned int rA = *(const unsigned int*)(rin + ia);
      const unsigned int kB = *(const unsigned int*)(kin + ib);
      const unsigned int vB = *(const unsigned int*)(vin + ib);
      const unsigned int rB = *(const unsigned int*)(rin + ib);
      float y0, y1;
      Y_STEP(w0, u0, blo(kA), blo(vA), blo(rA), pA0, qA0, oA0, y0)
      Y_STEP(w1, u1, bhi(kA), bhi(vA), bhi(rA), pA1, qA1, oA1, y1)
      const unsigned int zoA = (unsigned int)f2bf(y0) | (((unsigned int)f2bf(y1)) << 16);
      Y_STEP(w0, u0, blo(kB), blo(vB), blo(rB), pB0, qB0, oB0, y0)
      Y_STEP(w1, u1, bhi(kB), bhi(vB), bhi(rB), pB1, qB1, oB1, y1)
      const unsigned int zoB = (unsigned int)f2bf(y0) | (((unsigned int)f2bf(y1)) << 16);
      *(unsigned int*)(z + ia) = zoA;
      *(unsigned int*)(z + ib) = zoB;
    }
  }
}

// ---------------------------------------------------------------------------
extern "C" void kernel_launch(void* const* d_in, const int* in_sizes, int n_in,
                              void* d_out, int out_size, void* d_ws,
                              size_t ws_size, hipStream_t stream) {
  const float* x   = (const float*)d_in[0];
  const float* td  = (const float*)d_in[1];
  const float* tf  = (const float*)d_in[2];
  const float* tmk = (const float*)d_in[3];
  const float* tmv = (const float*)d_in[4];
  const float* tmr = (const float*)d_in[5];
  const float* Wk  = (const float*)d_in[6];
  const float* Wv  = (const float*)d_in[7];
  const float* Wr  = (const float*)d_in[8];
  const float* Wo  = (const float*)d_in[9];

  const size_t nW = (size_t)C_ * C_;
  const size_t nM = (size_t)M_ * C_;

  // ws (244.5 MiB): [wbk wbv wbr wbo][xk][xv][xr][kbuf][vbuf]  (all bf16)
  // rbuf lives in d_out (bf16; consumed by wkv before final GEMM overwrites)
  // z overlays xv (dead after gemm_v)
  unsigned short* wbk  = (unsigned short*)d_ws;
  unsigned short* wbv  = wbk + nW;
  unsigned short* wbr  = wbv + nW;
  unsigned short* wbo  = wbr + nW;
  unsigned short* xk   = wbo + nW;
  unsigned short* xv   = xk + nM;
  unsigned short* xr   = xv + nM;
  unsigned short* kbuf = xr + nM;
  unsigned short* vbuf = kbuf + nM;
  unsigned short* rbuf = (unsigned short*)d_out;
  unsigned short* zb   = xv;   // reuse

  prep<<<WBLK + MBLK, 256, 0, stream>>>(x, tmk, tmv, tmr, Wk, Wv, Wr, Wo,
                                        wbk, wbv, wbr, wbo, xk, xv, xr);

  gemm8<1><<<GNB, 256, 0, stream>>>(xk, wbk, kbuf);   // xk dies
  gemm8<1><<<GNB, 256, 0, stream>>>(xv, wbv, vbuf);   // xv dies
  gemm8<1><<<GNB, 256, 0, stream>>>(xr, wbr, rbuf);   // -> d_out (bf16)

  wkv_scan<<<B_ * (C_ / 64), 512, 0, stream>>>(kbuf, vbuf, rbuf, td, tf, zb);

  gemm8<0><<<GNB, 256, 0, stream>>>(zb, wbo, d_out);  // f32 out
}